// Round 2
// baseline (12668.528 us; speedup 1.0000x reference)
//
#include <hip/hip_runtime.h>
#include <math.h>

// ---------------- dims ----------------
#define B_    4
#define N_    512
#define D_    256
#define H_    8
#define DH_   32
#define M_    110
#define MP_   112           // padded M (pads are exact zeros)
#define FF_   1024
#define HID_  256
#define ROWS_ 2048          // B*N
#define CHUNK 32
#define NCH   16            // N_/CHUNK

// ---------------- ws layout (float offsets) ----------------
#define OFF_H      0u         // 524288  current activations [2048][256]
#define OFF_Y      524288u    // 524288  LN output
#define OFF_Q      1048576u   // 524288
#define OFF_K      1572864u   // 524288
#define OFF_V      2097152u   // 524288
#define OFF_O      2621440u   // 524288  attn output
#define OFF_FF     3145728u   // 2097152 FF hidden; reused as BLa/BLb in LSTM phase
#define OFF_QP     5242880u   // 1835008 ; reused as gi (4194304) in LSTM phase
#define OFF_KP     7077888u   // 1835008
#define OFF_S      8912896u   // 1835008
#define OFF_P      10747904u  // 1835008
#define OFF_KSUM   12582912u  // 57344
#define OFF_PK     12640256u  // 57344
#define OFF_DIAG   12697600u  // 16384
#define OFF_KMAX   12713984u  // 64 (uints)
#define OFF_CTR    12714048u  // 512 (uints): 16 flags x 32-stride (128B lines)
#define OFF_HDBUF  12714560u  // 4096 [2][2][4][256]
// END = 12718656 floats = ~48.5 MiB

#define SCALE_X 0.42044820762685725f   // 32^-0.25
#define SCALE_M 0.09534625892455924f   // 110^-0.5

__device__ __forceinline__ float sigmoidf_(float x){ return 1.0f/(1.0f+expf(-x)); }
__device__ __forceinline__ float geluf_(float x){ return 0.5f*x*(1.0f+erff(x*0.70710678118654752f)); }
__device__ __forceinline__ unsigned encf_(float x){ unsigned u=__float_as_uint(x); return (u&0x80000000u)?~u:(u|0x80000000u); }
__device__ __forceinline__ float decf_(unsigned u){ return (u&0x80000000u)?__uint_as_float(u&0x7fffffffu):__uint_as_float(~u); }

// ================= GEMM A: BM=64,BN=64,BK=16, 4x4/thread, transposed LDS =================
// C[M,N] = act(A @ W^T + b1 + b2) + R ; grid (N/64, M/64)
__global__ __launch_bounds__(256) void gemmA_k(
    const float* __restrict__ A, const float* __restrict__ W,
    const float* __restrict__ b1, const float* __restrict__ b2,
    const float* __restrict__ R, float* __restrict__ C,
    int Np, int K, int act)
{
  __shared__ float As[16][68];
  __shared__ float Ws[16][68];
  const int t = threadIdx.x;
  const int i0 = blockIdx.y * 64, j0 = blockIdx.x * 64;
  const int sr = t >> 2, sk = (t & 3) << 2;      // staging: row, k-offset
  const int tn = t & 15, tm = t >> 4;            // compute: col-group, row-group
  const float* Arow = A + (size_t)(i0 + sr) * K + sk;
  const float* Wrow = W + (size_t)(j0 + sr) * K + sk;
  float acc[4][4] = {};
  for (int k0 = 0; k0 < K; k0 += 16) {
    float4 a4 = *(const float4*)(Arow + k0);
    float4 w4 = *(const float4*)(Wrow + k0);
    __syncthreads();
    As[sk+0][sr]=a4.x; As[sk+1][sr]=a4.y; As[sk+2][sr]=a4.z; As[sk+3][sr]=a4.w;
    Ws[sk+0][sr]=w4.x; Ws[sk+1][sr]=w4.y; Ws[sk+2][sr]=w4.z; Ws[sk+3][sr]=w4.w;
    __syncthreads();
    #pragma unroll
    for (int kk = 0; kk < 16; kk++) {
      float a[4], w[4];
      *(float4*)&a[0] = *(const float4*)&As[kk][tm*4];
      *(float4*)&w[0] = *(const float4*)&Ws[kk][tn*4];
      #pragma unroll
      for (int ii = 0; ii < 4; ii++)
        #pragma unroll
        for (int jj = 0; jj < 4; jj++)
          acc[ii][jj] += a[ii] * w[jj];
    }
  }
  const int col = j0 + tn*4;
  float4 bb = make_float4(0.f,0.f,0.f,0.f);
  if (b1) { float4 b_ = *(const float4*)(b1 + col); bb.x+=b_.x; bb.y+=b_.y; bb.z+=b_.z; bb.w+=b_.w; }
  if (b2) { float4 b_ = *(const float4*)(b2 + col); bb.x+=b_.x; bb.y+=b_.y; bb.z+=b_.z; bb.w+=b_.w; }
  #pragma unroll
  for (int ii = 0; ii < 4; ii++) {
    const int row = i0 + tm*4 + ii;
    float4 o;
    o.x = acc[ii][0] + bb.x; o.y = acc[ii][1] + bb.y;
    o.z = acc[ii][2] + bb.z; o.w = acc[ii][3] + bb.w;
    if (act) { o.x = geluf_(o.x); o.y = geluf_(o.y); o.z = geluf_(o.z); o.w = geluf_(o.w); }
    if (R) {
      float4 r4 = *(const float4*)(R + (size_t)row * Np + col);
      o.x += r4.x; o.y += r4.y; o.z += r4.z; o.w += r4.w;
    }
    *(float4*)(C + (size_t)row * Np + col) = o;
  }
}

// ================= GEMM B: BM=128,BN=64,BK=16, 8x4/thread, up to 3 segments =================
// grid (segs*(Nseg/64), M/128); seg = bx / blkPerSeg
__global__ __launch_bounds__(256) void gemmB_k(
    const float* __restrict__ A,
    const float* __restrict__ W0, const float* __restrict__ W1, const float* __restrict__ W2,
    const float* __restrict__ p10, const float* __restrict__ p11, const float* __restrict__ p12,
    const float* __restrict__ p20, const float* __restrict__ p21, const float* __restrict__ p22,
    float* __restrict__ C0, float* __restrict__ C1, float* __restrict__ C2,
    int Np, int K, int blkPerSeg, int act)
{
  __shared__ float As[16][132];
  __shared__ float Ws[16][68];
  const int t = threadIdx.x;
  const int seg = blockIdx.x / blkPerSeg;
  const int j0 = (blockIdx.x - seg * blkPerSeg) * 64;
  const int i0 = blockIdx.y * 128;
  const float* W  = (seg == 0) ? W0 : (seg == 1) ? W1 : W2;
  const float* b1 = (seg == 0) ? p10 : (seg == 1) ? p11 : p12;
  const float* b2 = (seg == 0) ? p20 : (seg == 1) ? p21 : p22;
  float*       C  = (seg == 0) ? C0 : (seg == 1) ? C1 : C2;
  const int ar = t >> 1, ak = (t & 1) << 3;      // A staging: 2 float4/thread
  const int wr = t >> 2, wk = (t & 3) << 2;      // W staging: 1 float4/thread
  const int tn = t & 15, tm = t >> 4;            // compute: cols tn*4, rows tm*8
  const float* Arow = A + (size_t)(i0 + ar) * K + ak;
  const float* Wrow = W + (size_t)(j0 + wr) * K + wk;
  float acc[8][4] = {};
  for (int k0 = 0; k0 < K; k0 += 16) {
    float4 a0 = *(const float4*)(Arow + k0);
    float4 a1 = *(const float4*)(Arow + k0 + 4);
    float4 w4 = *(const float4*)(Wrow + k0);
    __syncthreads();
    As[ak+0][ar]=a0.x; As[ak+1][ar]=a0.y; As[ak+2][ar]=a0.z; As[ak+3][ar]=a0.w;
    As[ak+4][ar]=a1.x; As[ak+5][ar]=a1.y; As[ak+6][ar]=a1.z; As[ak+7][ar]=a1.w;
    Ws[wk+0][wr]=w4.x; Ws[wk+1][wr]=w4.y; Ws[wk+2][wr]=w4.z; Ws[wk+3][wr]=w4.w;
    __syncthreads();
    #pragma unroll
    for (int kk = 0; kk < 16; kk++) {
      float a[8], w[4];
      *(float4*)&a[0] = *(const float4*)&As[kk][tm*8];
      *(float4*)&a[4] = *(const float4*)&As[kk][tm*8 + 4];
      *(float4*)&w[0] = *(const float4*)&Ws[kk][tn*4];
      #pragma unroll
      for (int ii = 0; ii < 8; ii++)
        #pragma unroll
        for (int jj = 0; jj < 4; jj++)
          acc[ii][jj] += a[ii] * w[jj];
    }
  }
  const int col = j0 + tn*4;
  float4 bb = make_float4(0.f,0.f,0.f,0.f);
  if (b1) { float4 b_ = *(const float4*)(b1 + col); bb.x+=b_.x; bb.y+=b_.y; bb.z+=b_.z; bb.w+=b_.w; }
  if (b2) { float4 b_ = *(const float4*)(b2 + col); bb.x+=b_.x; bb.y+=b_.y; bb.z+=b_.z; bb.w+=b_.w; }
  #pragma unroll
  for (int ii = 0; ii < 8; ii++) {
    const int row = i0 + tm*8 + ii;
    float4 o;
    o.x = acc[ii][0] + bb.x; o.y = acc[ii][1] + bb.y;
    o.z = acc[ii][2] + bb.z; o.w = acc[ii][3] + bb.w;
    if (act) { o.x = geluf_(o.x); o.y = geluf_(o.y); o.z = geluf_(o.z); o.w = geluf_(o.w); }
    *(float4*)(C + (size_t)row * Np + col) = o;
  }
}

// ---------------- LayerNorm: wave per row, grid 512 ----------------
__global__ __launch_bounds__(256) void ln_k(const float* __restrict__ x, const float* __restrict__ w,
                                            const float* __restrict__ b, float* __restrict__ y)
{
  const int wid = threadIdx.x >> 6, lane = threadIdx.x & 63;
  const int row = blockIdx.x * 4 + wid;
  float4 v = *(const float4*)(x + (size_t)row * 256 + lane * 4);
  float s = v.x + v.y + v.z + v.w;
  #pragma unroll
  for (int o = 32; o >= 1; o >>= 1) s += __shfl_xor(s, o, 64);
  const float mu = s * (1.0f/256.0f);
  float4 d = make_float4(v.x-mu, v.y-mu, v.z-mu, v.w-mu);
  float s2 = d.x*d.x + d.y*d.y + d.z*d.z + d.w*d.w;
  #pragma unroll
  for (int o = 32; o >= 1; o >>= 1) s2 += __shfl_xor(s2, o, 64);
  const float r = 1.0f / sqrtf(s2 * (1.0f/256.0f) + 1e-5f);
  float4 w4 = *(const float4*)(w + lane*4);
  float4 b4 = *(const float4*)(b + lane*4);
  float4 o4;
  o4.x = d.x*r*w4.x + b4.x; o4.y = d.y*r*w4.y + b4.y;
  o4.z = d.z*r*w4.z + b4.z; o4.w = d.w*r*w4.w + b4.w;
  *(float4*)(y + (size_t)row * 256 + lane*4) = o4;
}

// ---------------- FAVOR+ features, fused Q/K path (grid 8192) ----------------
__global__ __launch_bounds__(256) void featqk_k(const float* __restrict__ q, const float* __restrict__ kin,
    const float* __restrict__ proj, float* __restrict__ qp, float* __restrict__ kpraw,
    float* __restrict__ diagb, unsigned* __restrict__ kmax)
{
  const int wid = threadIdx.x >> 6, lane = threadIdx.x & 63;
  const bool isq = blockIdx.x < 4096;
  const int pb = isq ? blockIdx.x : (blockIdx.x - 4096);
  const int p = pb * 4 + wid;
  const int bh = p >> 9, n = p & 511;
  const int b = bh >> 3, h = bh & 7;
  __shared__ float xs[4][32];
  const float* src = (isq ? q : kin) + ((size_t)(b * N_ + n)) * D_ + h * DH_;
  if (lane < 32) xs[wid][lane] = src[lane] * SCALE_X;
  __syncthreads();
  float4 xv[8];
  #pragma unroll
  for (int i = 0; i < 8; i++) xv[i] = *(const float4*)&xs[wid][i*4];
  float diag = 0.f;
  #pragma unroll
  for (int i = 0; i < 8; i++) diag += xv[i].x*xv[i].x + xv[i].y*xv[i].y + xv[i].z*xv[i].z + xv[i].w*xv[i].w;
  diag *= 0.5f;
  const int m0 = lane, m1 = 64 + lane;
  float dd0 = 0.f, dd1 = -INFINITY;
  {
    const float4* pr = (const float4*)(proj + m0 * 32);
    float a = 0.f;
    #pragma unroll
    for (int i = 0; i < 8; i++) { float4 pv = pr[i]; a += xv[i].x*pv.x + xv[i].y*pv.y + xv[i].z*pv.z + xv[i].w*pv.w; }
    dd0 = a;
  }
  if (m1 < M_) {
    const float4* pr = (const float4*)(proj + m1 * 32);
    float a = 0.f;
    #pragma unroll
    for (int i = 0; i < 8; i++) { float4 pv = pr[i]; a += xv[i].x*pv.x + xv[i].y*pv.y + xv[i].z*pv.z + xv[i].w*pv.w; }
    dd1 = a;
  }
  float mx = fmaxf(dd0, dd1);
  #pragma unroll
  for (int o = 32; o >= 1; o >>= 1) mx = fmaxf(mx, __shfl_xor(mx, o, 64));
  if (isq) {
    float* out = qp + (size_t)p * MP_;
    out[m0] = SCALE_M * (expf(dd0 - diag - mx) + 1e-4f);
    if (m1 < M_)        out[m1] = SCALE_M * (expf(dd1 - diag - mx) + 1e-4f);
    else if (m1 < MP_)  out[m1] = 0.f;
  } else {
    float* out = kpraw + (size_t)p * MP_;
    out[m0] = dd0;
    if (m1 < M_) out[m1] = dd1;
    if (lane == 0) { diagb[p] = diag; atomicMax(kmax + bh, encf_(mx)); }
  }
}

// ---------------- key features pass 2: finalize ----------------
__global__ __launch_bounds__(256) void featk2_k(float* __restrict__ kp, const float* __restrict__ diagb,
                                                const unsigned* __restrict__ kmax)
{
  const int idx = blockIdx.x * 256 + threadIdx.x;      // < 16384*112
  const int p = idx / MP_, m = idx - p * MP_;
  const int bh = p >> 9;
  float v = 0.f;
  if (m < M_) v = SCALE_M * (expf(kp[idx] - diagb[p] - decf_(kmax[bh])) + 1e-4f);
  kp[idx] = v;
}

// ---------------- chunked linear attention: per-chunk K-state sums ----------------
__global__ __launch_bounds__(256) void csum_k(const float* __restrict__ kp, const float* __restrict__ v,
                                              float* __restrict__ S, float* __restrict__ ksum)
{
  const int bh = blockIdx.x >> 4, c = blockIdx.x & 15;
  const int b = bh >> 3, h = bh & 7;
  __shared__ float kpc[CHUNK * MP_];
  __shared__ float vc[CHUNK][DH_];
  const float* kpbase = kp + ((size_t)bh * N_ + c * CHUNK) * MP_;
  for (int f = threadIdx.x; f < CHUNK * MP_; f += 256) kpc[f] = kpbase[f];
  for (int f = threadIdx.x; f < CHUNK * DH_; f += 256) {
    int i = f >> 5, d = f & 31;
    vc[i][d] = v[((size_t)(b * N_ + c * CHUNK + i)) * D_ + h * DH_ + d];
  }
  __syncthreads();
  const int d = threadIdx.x & 31, mg = threadIdx.x >> 5;
  float Sa[14] = {};
  for (int i = 0; i < CHUNK; i++) {
    float vv = vc[i][d];
    #pragma unroll
    for (int j = 0; j < 14; j++) Sa[j] += kpc[i * MP_ + mg * 14 + j] * vv;
  }
  float* Sout = S + (((size_t)blockIdx.x) * MP_ + mg * 14) * DH_ + d;
  #pragma unroll
  for (int j = 0; j < 14; j++) Sout[(size_t)j * DH_] = Sa[j];
  if (threadIdx.x < MP_) {
    float s = 0.f;
    for (int i = 0; i < CHUNK; i++) s += kpc[i * MP_ + threadIdx.x];
    ksum[(size_t)blockIdx.x * MP_ + threadIdx.x] = s;
  }
}

// ---------------- exclusive prefix over chunks ----------------
__global__ __launch_bounds__(256) void cpref_k(const float* __restrict__ S, const float* __restrict__ ksum,
                                               float* __restrict__ P, float* __restrict__ pk)
{
  const int bh = blockIdx.x;
  const int d = threadIdx.x & 31, mg = threadIdx.x >> 5;
  float run[14] = {};
  for (int c = 0; c < NCH; c++) {
    size_t base = (((size_t)(bh * NCH + c)) * MP_ + mg * 14) * DH_ + d;
    #pragma unroll
    for (int j = 0; j < 14; j++) { P[base + (size_t)j * DH_] = run[j]; run[j] += S[base + (size_t)j * DH_]; }
  }
  if (threadIdx.x < MP_) {
    float r = 0.f;
    for (int c = 0; c < NCH; c++) {
      size_t o = (size_t)(bh * NCH + c) * MP_ + threadIdx.x;
      pk[o] = r; r += ksum[o];
    }
  }
}

// ---------------- intra-chunk causal attention + combine ----------------
__global__ __launch_bounds__(256, 1) void attn_k(const float* __restrict__ qp, const float* __restrict__ kp,
                                                 const float* __restrict__ v, const float* __restrict__ P,
                                                 const float* __restrict__ pk, float* __restrict__ o)
{
  const int bh = blockIdx.x >> 4, c = blockIdx.x & 15;
  const int b = bh >> 3, h = bh & 7;
  __shared__ float qpc[CHUNK * 113];
  __shared__ float kpc[CHUNK * 113];
  __shared__ float vc[CHUNK][DH_];
  __shared__ float Pl[MP_ * DH_];
  __shared__ float pkl[MP_];
  __shared__ float Al[CHUNK * 33];
  __shared__ float den[CHUNK];
  const int t = threadIdx.x;
  const float* qbase = qp + ((size_t)bh * N_ + c * CHUNK) * MP_;
  const float* kbase = kp + ((size_t)bh * N_ + c * CHUNK) * MP_;
  for (int f = t; f < CHUNK * MP_; f += 256) {
    int i = f / MP_, m = f - i * MP_;
    qpc[i * 113 + m] = qbase[f];
    kpc[i * 113 + m] = kbase[f];
  }
  for (int f = t; f < CHUNK * DH_; f += 256) {
    int i = f >> 5, d = f & 31;
    vc[i][d] = v[((size_t)(b * N_ + c * CHUNK + i)) * D_ + h * DH_ + d];
  }
  for (int f = t; f < MP_ * DH_; f += 256) Pl[f] = P[((size_t)blockIdx.x) * MP_ * DH_ + f];
  if (t < MP_) pkl[t] = pk[(size_t)blockIdx.x * MP_ + t];
  __syncthreads();
  { // causal score tile 2x2 per thread
    const int ti = t >> 4, tj = t & 15;
    float a00 = 0.f, a01 = 0.f, a10 = 0.f, a11 = 0.f;
    for (int m = 0; m < MP_; m++) {
      float q0 = qpc[(ti*2+0)*113 + m], q1 = qpc[(ti*2+1)*113 + m];
      float k0 = kpc[(tj*2+0)*113 + m], k1 = kpc[(tj*2+1)*113 + m];
      a00 += q0*k0; a01 += q0*k1; a10 += q1*k0; a11 += q1*k1;
    }
    const int i0_ = ti*2, j0_ = tj*2;
    Al[(i0_  )*33 + j0_  ] = (j0_   <= i0_  ) ? a00 : 0.f;
    Al[(i0_  )*33 + j0_+1] = (j0_+1 <= i0_  ) ? a01 : 0.f;
    Al[(i0_+1)*33 + j0_  ] = (j0_   <= i0_+1) ? a10 : 0.f;
    Al[(i0_+1)*33 + j0_+1] = (j0_+1 <= i0_+1) ? a11 : 0.f;
  }
  __syncthreads();
  if (t < CHUNK) {
    const int i = t; float s = 0.f;
    for (int m = 0; m < MP_; m++) s += qpc[i*113 + m] * pkl[m];
    for (int j = 0; j <= i; j++) s += Al[i*33 + j];
    den[i] = 1.0f / (s + 1e-6f);
  }
  __syncthreads();
  {
    const int d = t & 31, ig = t >> 5;
    float Pd[MP_];
    #pragma unroll
    for (int m = 0; m < MP_; m++) Pd[m] = Pl[m * DH_ + d];
    float vd[CHUNK];
    #pragma unroll
    for (int j = 0; j < CHUNK; j++) vd[j] = vc[j][d];
    for (int r = 0; r < 4; r++) {
      const int i = ig * 4 + r;
      float acc = 0.f;
      #pragma unroll
      for (int m = 0; m < MP_; m++) acc += qpc[i*113 + m] * Pd[m];
      #pragma unroll
      for (int j = 0; j < CHUNK; j++) acc += Al[i*33 + j] * vd[j];
      o[((size_t)(b * N_ + c * CHUNK + i)) * D_ + h * DH_ + d] = acc * den[i];
    }
  }
}

// ---------------- BiLSTM recurrence: 16 blocks (8/dir); flag barrier + shuffle reduce ----------------
__global__ __launch_bounds__(256, 1) void rec_k(
    const float* __restrict__ gi, const float* __restrict__ whh,
    float* __restrict__ hs, float* __restrict__ hd, unsigned* __restrict__ ctr)
{
  const int t = threadIdx.x;
  const int dir = blockIdx.x >> 3;
  const int s = blockIdx.x & 7;
  const float* giD = gi + (size_t)dir * 2097152;
  const float* whD = whh + (size_t)dir * 262144;
  float* hdD = hd + dir * 2048;         // [2][4][256]
  unsigned* ctrD = ctr + dir * 256;     // 8 flags x 32-uint stride

  __shared__ __align__(16) float h_sh[4 * 288];   // [b]*288 + kq*36 + i  (padded: conflict-free)
  __shared__ __align__(16) float gsh[512];        // [rho*4 + b]

  // thread roles: kq = k-slice (lane bits 0..2), rg = row group
  const int kq = t & 7, rg = t >> 3;

  // Register-resident Whh slice: rows rho = rg*4+rr, k in [kq*32, kq*32+32)
  float4 w4r[4][8];
  #pragma unroll
  for (int rr = 0; rr < 4; rr++) {
    const int rho = rg * 4 + rr;
    const int g = (rho >> 5) * 256 + s * 32 + (rho & 31);
    const float4* src = (const float4*)(whD + (size_t)g * 256 + kq * 32);
    #pragma unroll
    for (int q = 0; q < 8; q++) w4r[rr][q] = src[q];
  }

  // initial h (buffer 0 zeroed by host memset)
  {
    const int f = t * 4;
    const int b = f >> 8, idx = f & 255, k2 = idx >> 5, i = idx & 31;
    float4 hv;
    hv.x = __hip_atomic_load(hdD + f + 0, __ATOMIC_RELAXED, __HIP_MEMORY_SCOPE_AGENT);
    hv.y = __hip_atomic_load(hdD + f + 1, __ATOMIC_RELAXED, __HIP_MEMORY_SCOPE_AGENT);
    hv.z = __hip_atomic_load(hdD + f + 2, __ATOMIC_RELAXED, __HIP_MEMORY_SCOPE_AGENT);
    hv.w = __hip_atomic_load(hdD + f + 3, __ATOMIC_RELAXED, __HIP_MEMORY_SCOPE_AGENT);
    *(float4*)&h_sh[b * 288 + k2 * 36 + i] = hv;
  }
  float c0 = 0.f;   // cell state for thread (t<128): b2 = t>>5, jj = t&31
  const int jj = t & 31, b2 = t >> 5;
  const int gcol = (t >> 5) * 256 + s * 32 + (t & 31);   // valid for t<128
  __syncthreads();

  // preload gi for step 0
  float gval[4];
  if (t < 128) {
    const int n0 = dir ? 511 : 0;
    #pragma unroll
    for (int b = 0; b < 4; b++) gval[b] = giD[(size_t)(b * 512 + n0) * 1024 + gcol];
  }

  int wb = 1;
  for (int step = 0; step < 512; step++) {
    const int n = dir ? (511 - step) : step;
    // matvec partials over this thread's k-slice
    float acc[4][4] = {};
    #pragma unroll
    for (int q = 0; q < 8; q++) {
      float4 h0 = *(const float4*)&h_sh[0*288 + kq*36 + q*4];
      float4 h1 = *(const float4*)&h_sh[1*288 + kq*36 + q*4];
      float4 h2 = *(const float4*)&h_sh[2*288 + kq*36 + q*4];
      float4 h3 = *(const float4*)&h_sh[3*288 + kq*36 + q*4];
      #pragma unroll
      for (int rr = 0; rr < 4; rr++) {
        float4 w = w4r[rr][q];
        acc[rr][0] += w.x*h0.x + w.y*h0.y + w.z*h0.z + w.w*h0.w;
        acc[rr][1] += w.x*h1.x + w.y*h1.y + w.z*h1.z + w.w*h1.w;
        acc[rr][2] += w.x*h2.x + w.y*h2.y + w.z*h2.z + w.w*h2.w;
        acc[rr][3] += w.x*h3.x + w.y*h3.y + w.z*h3.z + w.w*h3.w;
      }
    }
    // reduce across kq (lane bits 0..2) in-register
    #pragma unroll
    for (int m = 1; m <= 4; m <<= 1) {
      #pragma unroll
      for (int rr = 0; rr < 4; rr++) {
        #pragma unroll
        for (int b = 0; b < 4; b++)
          acc[rr][b] += __shfl_xor(acc[rr][b], m, 64);
      }
    }
    if (kq == 0) {
      #pragma unroll
      for (int rr = 0; rr < 4; rr++) {
        const int rho = rg * 4 + rr;
        *(float4*)&gsh[rho * 4] = make_float4(acc[rr][0], acc[rr][1], acc[rr][2], acc[rr][3]);
      }
    }
    __syncthreads();
    if (t < 128) {
      const float iv = gsh[(0 * 32 + jj) * 4 + b2] + gval[0*0];   // placeholder to keep shape
      // gate pre-activations: matvec part from gsh + input part gval[b2]? NO — gval is per-batch.
      // correct: this thread handles (b2, jj) -> needs all four gates for (b2, jj):
      const float g_i = gsh[(0 * 32 + jj) * 4 + b2];
      const float g_f = gsh[(1 * 32 + jj) * 4 + b2];
      const float g_g = gsh[(2 * 32 + jj) * 4 + b2];
      const float g_o = gsh[(3 * 32 + jj) * 4 + b2];
      (void)iv;
      // input parts: gval[] holds gi for rows gcol=(gate=t>>5)... -> that's per-gate, not per-batch.
      // We need gi for (b2, all 4 gates, col jj): stage gval through LDS reuse below.
      // To avoid an extra stage: gval[b] for this thread is gi[b][gate = t>>5][col jj] — matches the
      // gsh layout if we add it BEFORE the redistribution. Do that instead: (handled below)
      const float iv2 = g_i, fv2 = g_f, gg2 = g_g, ov2 = g_o;
      // add gi parts read directly (L2-resident, written just before by GEMM):
      const float ivf = iv2 + giD[(size_t)(b2 * 512 + n) * 1024 + 0 * 256 + s * 32 + jj];
      const float fvf = fv2 + giD[(size_t)(b2 * 512 + n) * 1024 + 1 * 256 + s * 32 + jj];
      const float ggf = gg2 + giD[(size_t)(b2 * 512 + n) * 1024 + 2 * 256 + s * 32 + jj];
      const float ovf = ov2 + giD[(size_t)(b2 * 512 + n) * 1024 + 3 * 256 + s * 32 + jj];
      (void)gval;
      c0 = sigmoidf_(fvf) * c0 + sigmoidf_(ivf) * tanhf(ggf);
      const float hv = sigmoidf_(ovf) * tanhf(c0);
      __hip_atomic_store(hdD + wb * 1024 + b2 * 256 + s * 32 + jj, hv,
                         __ATOMIC_RELAXED, __HIP_MEMORY_SCOPE_AGENT);
      hs[(size_t)(b2 * 512 + n) * 512 + dir * 256 + s * 32 + jj] = hv;
    }
    __syncthreads();   // all waves' stores drained (vmcnt) before flag publication
    if (t == 0) {
      __hip_atomic_store(ctrD + s * 32, (unsigned)(step + 1),
                         __ATOMIC_RELEASE, __HIP_MEMORY_SCOPE_AGENT);
    }
    // pollers on wave 2 (no vmcnt entanglement with wave 0/1)
    if (t >= 128 && t < 136) {
      const unsigned target = (unsigned)(step + 1);
      while (__hip_atomic_load(ctrD + (t - 128) * 32, __ATOMIC_ACQUIRE, __HIP_MEMORY_SCOPE_AGENT) < target)
        __builtin_amdgcn_s_sleep(1);
    }
    __syncthreads();
    // reload h
    {
      const int f = t * 4;
      const int b = f >> 8, idx = f & 255, k2 = idx >> 5, i = idx & 31;
      float4 hv;
      hv.x = __hip_atomic_load(hdD + wb * 1024 + f + 0, __ATOMIC_RELAXED, __HIP_MEMORY_SCOPE_AGENT);
      hv.y = __hip_atomic_load(hdD + wb * 1024 + f + 1, __ATOMIC_RELAXED, __HIP_MEMORY_SCOPE_AGENT);
      hv.z = __hip_atomic_load(hdD + wb * 1024 + f + 2, __ATOMIC_RELAXED, __HIP_MEMORY_SCOPE_AGENT);
      hv.w = __hip_atomic_load(hdD + wb * 1024 + f + 3, __ATOMIC_RELAXED, __HIP_MEMORY_SCOPE_AGENT);
      *(float4*)&h_sh[b * 288 + k2 * 36 + i] = hv;
    }
    __syncthreads();
    wb ^= 1;
  }
}

// ---------------- final head ----------------
__global__ __launch_bounds__(256) void fc_k(const float* __restrict__ hs, const float* __restrict__ fw,
                                            const float* __restrict__ fb, float* __restrict__ out)
{
  const int t = threadIdx.x;
  float p[4] = {};
  for (int j = t; j < 512; j += 256) {
    const float w = fw[j];
    #pragma unroll
    for (int b = 0; b < 4; b++) p[b] += hs[(size_t)(b * 512 + 511) * 512 + j] * w;
  }
  #pragma unroll
  for (int b = 0; b < 4; b++)
    #pragma unroll
    for (int o = 32; o >= 1; o >>= 1) p[b] += __shfl_xor(p[b], o, 64);
  __shared__ float r4[4][4];
  const int wid = t >> 6, lane = t & 63;
  if (lane == 0) {
    #pragma unroll
    for (int b = 0; b < 4; b++) r4[b][wid] = p[b];
  }
  __syncthreads();
  if (t == 0) {
    #pragma unroll
    for (int b = 0; b < 4; b++) out[b] = r4[b][0] + r4[b][1] + r4[b][2] + r4[b][3] + fb[0];
  }
}

// ---------------- host ----------------
extern "C" void kernel_launch(void* const* d_in, const int* in_sizes, int n_in,
                              void* d_out, int out_size, void* d_ws, size_t ws_size,
                              hipStream_t stream) {
  (void)in_sizes; (void)n_in; (void)out_size; (void)ws_size;
  const float* x     = (const float*)d_in[0];
  const float* Win_w = (const float*)d_in[1];
  const float* Win_b = (const float*)d_in[2];
  const float* ln1w  = (const float*)d_in[3];
  const float* ln1b  = (const float*)d_in[4];
  const float* Wq    = (const float*)d_in[5];
  const float* bq    = (const float*)d_in[6];
  const float* Wk    = (const float*)d_in[7];
  const float* bk    = (const float*)d_in[8];
  const float* Wv    = (const float*)d_in[9];
  const float* bv    = (const float*)d_in[10];
  const float* Wo    = (const float*)d_in[11];
  const float* bo    = (const float*)d_in[12];
  const float* proj  = (const float*)d_in[13];
  const float* ln2w  = (const float*)d_in[14];
  const float* ln2b  = (const float*)d_in[15];
  const float* Wff1  = (const float*)d_in[16];
  const float* bff1  = (const float*)d_in[17];
  const float* Wff2  = (const float*)d_in[18];
  const float* bff2  = (const float*)d_in[19];
  const float* Wih0  = (const float*)d_in[20];
  const float* Whh0  = (const float*)d_in[21];
  const float* b0    = (const float*)d_in[22];
  const float* Wih12 = (const float*)d_in[23];
  const float* Whh12 = (const float*)d_in[24];
  const float* b12   = (const float*)d_in[25];
  const float* fcw   = (const float*)d_in[26];
  const float* fcb   = (const float*)d_in[27];

  float* ws = (float*)d_ws;
  float* H   = ws + OFF_H;
  float* Y   = ws + OFF_Y;
  float* Q   = ws + OFF_Q;
  float* Kb  = ws + OFF_K;
  float* V   = ws + OFF_V;
  float* O   = ws + OFF_O;
  float* FFb = ws + OFF_FF;
  float* QP  = ws + OFF_QP;
  float* KP  = ws + OFF_KP;
  float* S   = ws + OFF_S;
  float* P   = ws + OFF_P;
  float* KS  = ws + OFF_KSUM;
  float* PK  = ws + OFF_PK;
  float* DG  = ws + OFF_DIAG;
  unsigned* KMAX = (unsigned*)(ws + OFF_KMAX);
  unsigned* CTR  = (unsigned*)(ws + OFF_CTR);
  float* HD  = ws + OFF_HDBUF;
  float* GI  = ws + OFF_QP;            // reused in LSTM phase
  float* BLa = ws + OFF_FF;            // reused in LSTM phase
  float* BLb = ws + OFF_FF + 1048576;

  const dim3 blk(256);

  // input projection: N=256, K=128
  gemmA_k<<<dim3(4,32), blk, 0, stream>>>(x, Win_w, Win_b, nullptr, nullptr, H, 256, 128, 0);

  for (int l = 0; l < 8; l++) {
    const float* prj = proj + (size_t)l * 3520;
    ln_k<<<512, blk, 0, stream>>>(H, ln1w + l*256, ln1b + l*256, Y);
    // fused QKV: 3 segments of N=256
    gemmB_k<<<dim3(12,16), blk, 0, stream>>>(Y,
        Wq + (size_t)l*65536, Wk + (size_t)l*65536, Wv + (size_t)l*65536,
        bq + l*256, bk + l*256, bv + l*256,
        nullptr, nullptr, nullptr,
        Q, Kb, V, 256, 256, 4, 0);
    (void)hipMemsetAsync(KMAX, 0, 32 * sizeof(unsigned), stream);
    featqk_k<<<8192, blk, 0, stream>>>(Q, Kb, prj, QP, KP, DG, KMAX);
    featk2_k<<<7168, blk, 0, stream>>>(KP, DG, KMAX);
    csum_k<<<512, blk, 0, stream>>>(KP, V, S, KS);
    cpref_k<<<32, blk, 0, stream>>>(S, KS, P, PK);
    attn_k<<<512, blk, 0, stream>>>(QP, KP, V, P, PK, O);
    gemmA_k<<<dim3(4,32), blk, 0, stream>>>(O, Wo + (size_t)l*65536, bo + l*256, nullptr, H, H, 256, 256, 0);
    ln_k<<<512, blk, 0, stream>>>(H, ln2w + l*256, ln2b + l*256, Y);
    gemmB_k<<<dim3(16,16), blk, 0, stream>>>(Y,
        Wff1 + (size_t)l*262144, nullptr, nullptr,
        bff1 + l*1024, nullptr, nullptr,
        nullptr, nullptr, nullptr,
        FFb, nullptr, nullptr, 1024, 256, 16, 1);
    gemmA_k<<<dim3(4,32), blk, 0, stream>>>(FFb, Wff2 + (size_t)l*262144, bff2 + l*256, nullptr, H, H, 256, 1024, 0);
  }

  // ---- BiLSTM layer 0 (input H, K=256): fused both directions ----
  gemmB_k<<<dim3(32,16), blk, 0, stream>>>(H,
      Wih0, Wih0 + 262144, nullptr,
      b0, b0 + 2048, nullptr,
      b0 + 1024, b0 + 3072, nullptr,
      GI, GI + 2097152, nullptr, 1024, 256, 16, 0);
  (void)hipMemsetAsync(CTR, 0, (512 + 4096) * sizeof(float), stream);
  rec_k<<<16, blk, 0, stream>>>(GI, Whh0, BLa, HD, CTR);

  // ---- layer 1 (input BLa, K=512) ----
  gemmB_k<<<dim3(32,16), blk, 0, stream>>>(BLa,
      Wih12, Wih12 + 524288, nullptr,
      b12, b12 + 2048, nullptr,
      b12 + 1024, b12 + 3072, nullptr,
      GI, GI + 2097152, nullptr, 1024, 512, 16, 0);
  (void)hipMemsetAsync(CTR, 0, (512 + 4096) * sizeof(float), stream);
  rec_k<<<16, blk, 0, stream>>>(GI, Whh12, BLb, HD, CTR);

  // ---- layer 2 (input BLb, K=512) ----
  gemmB_k<<<dim3(32,16), blk, 0, stream>>>(BLb,
      Wih12 + 1048576, Wih12 + 1572864, nullptr,
      b12 + 4096, b12 + 6144, nullptr,
      b12 + 5120, b12 + 7168, nullptr,
      GI, GI + 2097152, nullptr, 1024, 512, 16, 0);
  (void)hipMemsetAsync(CTR, 0, (512 + 4096) * sizeof(float), stream);
  rec_k<<<16, blk, 0, stream>>>(GI, Whh12 + 524288, BLa, HD, CTR);

  fc_k<<<1, blk, 0, stream>>>(BLa, fcw, fcb, (float*)d_out);
}

// Round 3
// 10732.294 us; speedup vs baseline: 1.1804x; 1.1804x over previous
//
#include <hip/hip_runtime.h>
#include <math.h>

// ---------------- dims ----------------
#define B_    4
#define N_    512
#define D_    256
#define H_    8
#define DH_   32
#define M_    110
#define MP_   112           // padded M (pads are exact zeros)
#define FF_   1024
#define HID_  256
#define ROWS_ 2048          // B*N
#define CHUNK 32
#define NCH   16            // N_/CHUNK

// ---------------- ws layout (float offsets) ----------------
#define OFF_H      0u         // 524288  current activations [2048][256]
#define OFF_Y      524288u    // 524288  LN output
#define OFF_Q      1048576u   // 524288
#define OFF_K      1572864u   // 524288
#define OFF_V      2097152u   // 524288
#define OFF_O      2621440u   // 524288  attn output
#define OFF_FF     3145728u   // 2097152 FF hidden; reused as BLa/BLb in LSTM phase
#define OFF_QP     5242880u   // 1835008 ; reused as gi (4194304) in LSTM phase
#define OFF_KP     7077888u   // 1835008
#define OFF_S      8912896u   // 1835008
#define OFF_P      10747904u  // 1835008
#define OFF_KSUM   12582912u  // 57344
#define OFF_PK     12640256u  // 57344
#define OFF_DIAG   12697600u  // 16384
#define OFF_KMAX   12713984u  // 64 (uints)
#define OFF_HDBUF  12714048u  // 8192 floats = [2 dirs][2 bufs][1024] uint64 tagged h
// END = 12722240 floats = ~48.5 MiB

#define SCALE_X 0.42044820762685725f   // 32^-0.25
#define SCALE_M 0.09534625892455924f   // 110^-0.5

__device__ __forceinline__ float sigmoidf_(float x){ return 1.0f/(1.0f+expf(-x)); }
__device__ __forceinline__ float geluf_(float x){ return 0.5f*x*(1.0f+erff(x*0.70710678118654752f)); }
__device__ __forceinline__ unsigned encf_(float x){ unsigned u=__float_as_uint(x); return (u&0x80000000u)?~u:(u|0x80000000u); }
__device__ __forceinline__ float decf_(unsigned u){ return (u&0x80000000u)?__uint_as_float(u&0x7fffffffu):__uint_as_float(~u); }

// ================= GEMM A: BM=64,BN=64,BK=16, 4x4/thread, transposed LDS =================
// C[M,N] = act(A @ W^T + b1 + b2) + R ; grid (N/64, M/64)
__global__ __launch_bounds__(256) void gemmA_k(
    const float* __restrict__ A, const float* __restrict__ W,
    const float* __restrict__ b1, const float* __restrict__ b2,
    const float* __restrict__ R, float* __restrict__ C,
    int Np, int K, int act)
{
  __shared__ float As[16][68];
  __shared__ float Ws[16][68];
  const int t = threadIdx.x;
  const int i0 = blockIdx.y * 64, j0 = blockIdx.x * 64;
  const int sr = t >> 2, sk = (t & 3) << 2;      // staging: row, k-offset
  const int tn = t & 15, tm = t >> 4;            // compute: col-group, row-group
  const float* Arow = A + (size_t)(i0 + sr) * K + sk;
  const float* Wrow = W + (size_t)(j0 + sr) * K + sk;
  float acc[4][4] = {};
  for (int k0 = 0; k0 < K; k0 += 16) {
    float4 a4 = *(const float4*)(Arow + k0);
    float4 w4 = *(const float4*)(Wrow + k0);
    __syncthreads();
    As[sk+0][sr]=a4.x; As[sk+1][sr]=a4.y; As[sk+2][sr]=a4.z; As[sk+3][sr]=a4.w;
    Ws[sk+0][sr]=w4.x; Ws[sk+1][sr]=w4.y; Ws[sk+2][sr]=w4.z; Ws[sk+3][sr]=w4.w;
    __syncthreads();
    #pragma unroll
    for (int kk = 0; kk < 16; kk++) {
      float a[4], w[4];
      *(float4*)&a[0] = *(const float4*)&As[kk][tm*4];
      *(float4*)&w[0] = *(const float4*)&Ws[kk][tn*4];
      #pragma unroll
      for (int ii = 0; ii < 4; ii++)
        #pragma unroll
        for (int jj = 0; jj < 4; jj++)
          acc[ii][jj] += a[ii] * w[jj];
    }
  }
  const int col = j0 + tn*4;
  float4 bb = make_float4(0.f,0.f,0.f,0.f);
  if (b1) { float4 b_ = *(const float4*)(b1 + col); bb.x+=b_.x; bb.y+=b_.y; bb.z+=b_.z; bb.w+=b_.w; }
  if (b2) { float4 b_ = *(const float4*)(b2 + col); bb.x+=b_.x; bb.y+=b_.y; bb.z+=b_.z; bb.w+=b_.w; }
  #pragma unroll
  for (int ii = 0; ii < 4; ii++) {
    const int row = i0 + tm*4 + ii;
    float4 o;
    o.x = acc[ii][0] + bb.x; o.y = acc[ii][1] + bb.y;
    o.z = acc[ii][2] + bb.z; o.w = acc[ii][3] + bb.w;
    if (act) { o.x = geluf_(o.x); o.y = geluf_(o.y); o.z = geluf_(o.z); o.w = geluf_(o.w); }
    if (R) {
      float4 r4 = *(const float4*)(R + (size_t)row * Np + col);
      o.x += r4.x; o.y += r4.y; o.z += r4.z; o.w += r4.w;
    }
    *(float4*)(C + (size_t)row * Np + col) = o;
  }
}

// ================= GEMM B: BM=128,BN=64,BK=16, 8x4/thread, up to 3 segments =================
// grid (segs*(Nseg/64), M/128); seg = bx / blkPerSeg
__global__ __launch_bounds__(256) void gemmB_k(
    const float* __restrict__ A,
    const float* __restrict__ W0, const float* __restrict__ W1, const float* __restrict__ W2,
    const float* __restrict__ p10, const float* __restrict__ p11, const float* __restrict__ p12,
    const float* __restrict__ p20, const float* __restrict__ p21, const float* __restrict__ p22,
    float* __restrict__ C0, float* __restrict__ C1, float* __restrict__ C2,
    int Np, int K, int blkPerSeg, int act)
{
  __shared__ float As[16][132];
  __shared__ float Ws[16][68];
  const int t = threadIdx.x;
  const int seg = blockIdx.x / blkPerSeg;
  const int j0 = (blockIdx.x - seg * blkPerSeg) * 64;
  const int i0 = blockIdx.y * 128;
  const float* W  = (seg == 0) ? W0 : (seg == 1) ? W1 : W2;
  const float* b1 = (seg == 0) ? p10 : (seg == 1) ? p11 : p12;
  const float* b2 = (seg == 0) ? p20 : (seg == 1) ? p21 : p22;
  float*       C  = (seg == 0) ? C0 : (seg == 1) ? C1 : C2;
  const int ar = t >> 1, ak = (t & 1) << 3;      // A staging: 2 float4/thread
  const int wr = t >> 2, wk = (t & 3) << 2;      // W staging: 1 float4/thread
  const int tn = t & 15, tm = t >> 4;            // compute: cols tn*4, rows tm*8
  const float* Arow = A + (size_t)(i0 + ar) * K + ak;
  const float* Wrow = W + (size_t)(j0 + wr) * K + wk;
  float acc[8][4] = {};
  for (int k0 = 0; k0 < K; k0 += 16) {
    float4 a0 = *(const float4*)(Arow + k0);
    float4 a1 = *(const float4*)(Arow + k0 + 4);
    float4 w4 = *(const float4*)(Wrow + k0);
    __syncthreads();
    As[ak+0][ar]=a0.x; As[ak+1][ar]=a0.y; As[ak+2][ar]=a0.z; As[ak+3][ar]=a0.w;
    As[ak+4][ar]=a1.x; As[ak+5][ar]=a1.y; As[ak+6][ar]=a1.z; As[ak+7][ar]=a1.w;
    Ws[wk+0][wr]=w4.x; Ws[wk+1][wr]=w4.y; Ws[wk+2][wr]=w4.z; Ws[wk+3][wr]=w4.w;
    __syncthreads();
    #pragma unroll
    for (int kk = 0; kk < 16; kk++) {
      float a[8], w[4];
      *(float4*)&a[0] = *(const float4*)&As[kk][tm*8];
      *(float4*)&a[4] = *(const float4*)&As[kk][tm*8 + 4];
      *(float4*)&w[0] = *(const float4*)&Ws[kk][tn*4];
      #pragma unroll
      for (int ii = 0; ii < 8; ii++)
        #pragma unroll
        for (int jj = 0; jj < 4; jj++)
          acc[ii][jj] += a[ii] * w[jj];
    }
  }
  const int col = j0 + tn*4;
  float4 bb = make_float4(0.f,0.f,0.f,0.f);
  if (b1) { float4 b_ = *(const float4*)(b1 + col); bb.x+=b_.x; bb.y+=b_.y; bb.z+=b_.z; bb.w+=b_.w; }
  if (b2) { float4 b_ = *(const float4*)(b2 + col); bb.x+=b_.x; bb.y+=b_.y; bb.z+=b_.z; bb.w+=b_.w; }
  #pragma unroll
  for (int ii = 0; ii < 8; ii++) {
    const int row = i0 + tm*8 + ii;
    float4 o;
    o.x = acc[ii][0] + bb.x; o.y = acc[ii][1] + bb.y;
    o.z = acc[ii][2] + bb.z; o.w = acc[ii][3] + bb.w;
    if (act) { o.x = geluf_(o.x); o.y = geluf_(o.y); o.z = geluf_(o.z); o.w = geluf_(o.w); }
    *(float4*)(C + (size_t)row * Np + col) = o;
  }
}

// ---------------- LayerNorm: wave per row, grid 512 ----------------
__global__ __launch_bounds__(256) void ln_k(const float* __restrict__ x, const float* __restrict__ w,
                                            const float* __restrict__ b, float* __restrict__ y)
{
  const int wid = threadIdx.x >> 6, lane = threadIdx.x & 63;
  const int row = blockIdx.x * 4 + wid;
  float4 v = *(const float4*)(x + (size_t)row * 256 + lane * 4);
  float s = v.x + v.y + v.z + v.w;
  #pragma unroll
  for (int o = 32; o >= 1; o >>= 1) s += __shfl_xor(s, o, 64);
  const float mu = s * (1.0f/256.0f);
  float4 d = make_float4(v.x-mu, v.y-mu, v.z-mu, v.w-mu);
  float s2 = d.x*d.x + d.y*d.y + d.z*d.z + d.w*d.w;
  #pragma unroll
  for (int o = 32; o >= 1; o >>= 1) s2 += __shfl_xor(s2, o, 64);
  const float r = 1.0f / sqrtf(s2 * (1.0f/256.0f) + 1e-5f);
  float4 w4 = *(const float4*)(w + lane*4);
  float4 b4 = *(const float4*)(b + lane*4);
  float4 o4;
  o4.x = d.x*r*w4.x + b4.x; o4.y = d.y*r*w4.y + b4.y;
  o4.z = d.z*r*w4.z + b4.z; o4.w = d.w*r*w4.w + b4.w;
  *(float4*)(y + (size_t)row * 256 + lane*4) = o4;
}

// ---------------- FAVOR+ features, fused Q/K path (grid 8192) ----------------
__global__ __launch_bounds__(256) void featqk_k(const float* __restrict__ q, const float* __restrict__ kin,
    const float* __restrict__ proj, float* __restrict__ qp, float* __restrict__ kpraw,
    float* __restrict__ diagb, unsigned* __restrict__ kmax)
{
  const int wid = threadIdx.x >> 6, lane = threadIdx.x & 63;
  const bool isq = blockIdx.x < 4096;
  const int pb = isq ? blockIdx.x : (blockIdx.x - 4096);
  const int p = pb * 4 + wid;
  const int bh = p >> 9, n = p & 511;
  const int b = bh >> 3, h = bh & 7;
  __shared__ float xs[4][32];
  const float* src = (isq ? q : kin) + ((size_t)(b * N_ + n)) * D_ + h * DH_;
  if (lane < 32) xs[wid][lane] = src[lane] * SCALE_X;
  __syncthreads();
  float4 xv[8];
  #pragma unroll
  for (int i = 0; i < 8; i++) xv[i] = *(const float4*)&xs[wid][i*4];
  float diag = 0.f;
  #pragma unroll
  for (int i = 0; i < 8; i++) diag += xv[i].x*xv[i].x + xv[i].y*xv[i].y + xv[i].z*xv[i].z + xv[i].w*xv[i].w;
  diag *= 0.5f;
  const int m0 = lane, m1 = 64 + lane;
  float dd0 = 0.f, dd1 = -INFINITY;
  {
    const float4* pr = (const float4*)(proj + m0 * 32);
    float a = 0.f;
    #pragma unroll
    for (int i = 0; i < 8; i++) { float4 pv = pr[i]; a += xv[i].x*pv.x + xv[i].y*pv.y + xv[i].z*pv.z + xv[i].w*pv.w; }
    dd0 = a;
  }
  if (m1 < M_) {
    const float4* pr = (const float4*)(proj + m1 * 32);
    float a = 0.f;
    #pragma unroll
    for (int i = 0; i < 8; i++) { float4 pv = pr[i]; a += xv[i].x*pv.x + xv[i].y*pv.y + xv[i].z*pv.z + xv[i].w*pv.w; }
    dd1 = a;
  }
  float mx = fmaxf(dd0, dd1);
  #pragma unroll
  for (int o = 32; o >= 1; o >>= 1) mx = fmaxf(mx, __shfl_xor(mx, o, 64));
  if (isq) {
    float* out = qp + (size_t)p * MP_;
    out[m0] = SCALE_M * (expf(dd0 - diag - mx) + 1e-4f);
    if (m1 < M_)        out[m1] = SCALE_M * (expf(dd1 - diag - mx) + 1e-4f);
    else if (m1 < MP_)  out[m1] = 0.f;
  } else {
    float* out = kpraw + (size_t)p * MP_;
    out[m0] = dd0;
    if (m1 < M_) out[m1] = dd1;
    if (lane == 0) { diagb[p] = diag; atomicMax(kmax + bh, encf_(mx)); }
  }
}

// ---------------- key features pass 2: finalize ----------------
__global__ __launch_bounds__(256) void featk2_k(float* __restrict__ kp, const float* __restrict__ diagb,
                                                const unsigned* __restrict__ kmax)
{
  const int idx = blockIdx.x * 256 + threadIdx.x;      // < 16384*112
  const int p = idx / MP_, m = idx - p * MP_;
  const int bh = p >> 9;
  float v = 0.f;
  if (m < M_) v = SCALE_M * (expf(kp[idx] - diagb[p] - decf_(kmax[bh])) + 1e-4f);
  kp[idx] = v;
}

// ---------------- chunked linear attention: per-chunk K-state sums ----------------
__global__ __launch_bounds__(256) void csum_k(const float* __restrict__ kp, const float* __restrict__ v,
                                              float* __restrict__ S, float* __restrict__ ksum)
{
  const int bh = blockIdx.x >> 4, c = blockIdx.x & 15;
  const int b = bh >> 3, h = bh & 7;
  __shared__ float kpc[CHUNK * MP_];
  __shared__ float vc[CHUNK][DH_];
  const float* kpbase = kp + ((size_t)bh * N_ + c * CHUNK) * MP_;
  for (int f = threadIdx.x; f < CHUNK * MP_; f += 256) kpc[f] = kpbase[f];
  for (int f = threadIdx.x; f < CHUNK * DH_; f += 256) {
    int i = f >> 5, d = f & 31;
    vc[i][d] = v[((size_t)(b * N_ + c * CHUNK + i)) * D_ + h * DH_ + d];
  }
  __syncthreads();
  const int d = threadIdx.x & 31, mg = threadIdx.x >> 5;
  float Sa[14] = {};
  for (int i = 0; i < CHUNK; i++) {
    float vv = vc[i][d];
    #pragma unroll
    for (int j = 0; j < 14; j++) Sa[j] += kpc[i * MP_ + mg * 14 + j] * vv;
  }
  float* Sout = S + (((size_t)blockIdx.x) * MP_ + mg * 14) * DH_ + d;
  #pragma unroll
  for (int j = 0; j < 14; j++) Sout[(size_t)j * DH_] = Sa[j];
  if (threadIdx.x < MP_) {
    float s = 0.f;
    for (int i = 0; i < CHUNK; i++) s += kpc[i * MP_ + threadIdx.x];
    ksum[(size_t)blockIdx.x * MP_ + threadIdx.x] = s;
  }
}

// ---------------- exclusive prefix over chunks ----------------
__global__ __launch_bounds__(256) void cpref_k(const float* __restrict__ S, const float* __restrict__ ksum,
                                               float* __restrict__ P, float* __restrict__ pk)
{
  const int bh = blockIdx.x;
  const int d = threadIdx.x & 31, mg = threadIdx.x >> 5;
  float run[14] = {};
  for (int c = 0; c < NCH; c++) {
    size_t base = (((size_t)(bh * NCH + c)) * MP_ + mg * 14) * DH_ + d;
    #pragma unroll
    for (int j = 0; j < 14; j++) { P[base + (size_t)j * DH_] = run[j]; run[j] += S[base + (size_t)j * DH_]; }
  }
  if (threadIdx.x < MP_) {
    float r = 0.f;
    for (int c = 0; c < NCH; c++) {
      size_t o = (size_t)(bh * NCH + c) * MP_ + threadIdx.x;
      pk[o] = r; r += ksum[o];
    }
  }
}

// ---------------- intra-chunk causal attention + combine ----------------
__global__ __launch_bounds__(256, 1) void attn_k(const float* __restrict__ qp, const float* __restrict__ kp,
                                                 const float* __restrict__ v, const float* __restrict__ P,
                                                 const float* __restrict__ pk, float* __restrict__ o)
{
  const int bh = blockIdx.x >> 4, c = blockIdx.x & 15;
  const int b = bh >> 3, h = bh & 7;
  __shared__ float qpc[CHUNK * 113];
  __shared__ float kpc[CHUNK * 113];
  __shared__ float vc[CHUNK][DH_];
  __shared__ float Pl[MP_ * DH_];
  __shared__ float pkl[MP_];
  __shared__ float Al[CHUNK * 33];
  __shared__ float den[CHUNK];
  const int t = threadIdx.x;
  const float* qbase = qp + ((size_t)bh * N_ + c * CHUNK) * MP_;
  const float* kbase = kp + ((size_t)bh * N_ + c * CHUNK) * MP_;
  for (int f = t; f < CHUNK * MP_; f += 256) {
    int i = f / MP_, m = f - i * MP_;
    qpc[i * 113 + m] = qbase[f];
    kpc[i * 113 + m] = kbase[f];
  }
  for (int f = t; f < CHUNK * DH_; f += 256) {
    int i = f >> 5, d = f & 31;
    vc[i][d] = v[((size_t)(b * N_ + c * CHUNK + i)) * D_ + h * DH_ + d];
  }
  for (int f = t; f < MP_ * DH_; f += 256) Pl[f] = P[((size_t)blockIdx.x) * MP_ * DH_ + f];
  if (t < MP_) pkl[t] = pk[(size_t)blockIdx.x * MP_ + t];
  __syncthreads();
  { // causal score tile 2x2 per thread
    const int ti = t >> 4, tj = t & 15;
    float a00 = 0.f, a01 = 0.f, a10 = 0.f, a11 = 0.f;
    for (int m = 0; m < MP_; m++) {
      float q0 = qpc[(ti*2+0)*113 + m], q1 = qpc[(ti*2+1)*113 + m];
      float k0 = kpc[(tj*2+0)*113 + m], k1 = kpc[(tj*2+1)*113 + m];
      a00 += q0*k0; a01 += q0*k1; a10 += q1*k0; a11 += q1*k1;
    }
    const int i0_ = ti*2, j0_ = tj*2;
    Al[(i0_  )*33 + j0_  ] = (j0_   <= i0_  ) ? a00 : 0.f;
    Al[(i0_  )*33 + j0_+1] = (j0_+1 <= i0_  ) ? a01 : 0.f;
    Al[(i0_+1)*33 + j0_  ] = (j0_   <= i0_+1) ? a10 : 0.f;
    Al[(i0_+1)*33 + j0_+1] = (j0_+1 <= i0_+1) ? a11 : 0.f;
  }
  __syncthreads();
  if (t < CHUNK) {
    const int i = t; float s = 0.f;
    for (int m = 0; m < MP_; m++) s += qpc[i*113 + m] * pkl[m];
    for (int j = 0; j <= i; j++) s += Al[i*33 + j];
    den[i] = 1.0f / (s + 1e-6f);
  }
  __syncthreads();
  {
    const int d = t & 31, ig = t >> 5;
    float Pd[MP_];
    #pragma unroll
    for (int m = 0; m < MP_; m++) Pd[m] = Pl[m * DH_ + d];
    float vd[CHUNK];
    #pragma unroll
    for (int j = 0; j < CHUNK; j++) vd[j] = vc[j][d];
    for (int r = 0; r < 4; r++) {
      const int i = ig * 4 + r;
      float acc = 0.f;
      #pragma unroll
      for (int m = 0; m < MP_; m++) acc += qpc[i*113 + m] * Pd[m];
      #pragma unroll
      for (int j = 0; j < CHUNK; j++) acc += Al[i*33 + j] * vd[j];
      o[((size_t)(b * N_ + c * CHUNK + i)) * D_ + h * DH_ + d] = acc * den[i];
    }
  }
}

// ---------------- BiLSTM recurrence: 16 blocks (8/dir) ----------------
// Sync via tagged 64-bit h words: (step_tag<<32)|float_bits, relaxed agent atomics only.
// No acquire/release in the loop -> no L2 invalidates. Double-buffered by (step+1)&1.
__global__ __launch_bounds__(256, 1) void rec_k(
    const float* __restrict__ gi, const float* __restrict__ whh,
    float* __restrict__ hs, unsigned long long* __restrict__ hd)
{
  const int t = threadIdx.x;
  const int dir = blockIdx.x >> 3;
  const int s = blockIdx.x & 7;
  const float* giD = gi + (size_t)dir * 2097152;
  const float* whD = whh + (size_t)dir * 262144;
  unsigned long long* hdD = hd + dir * 2048;   // [2 bufs][1024]

  __shared__ __align__(16) float h_sh[4 * 288];   // [b]*288 + k2*36 + i  (padded: conflict-free)
  __shared__ __align__(16) float gsh[512];        // [(gate*32+jj)*4 + b]

  // thread roles
  const int kq = t & 7, rg = t >> 3;              // matvec: k-slice, row-group
  const int jj = t & 31, b2 = t >> 5;             // gate phase (t<128): col, batch
  const int cb = t >> 6;                          // consumer: batch
  const int ck = (t >> 3) & 7;                    // consumer: k2 slice (block owner)
  const int ci = (t & 7) * 4;                     // consumer: first col within slice

  // Register-resident Whh slice: rows rho = rg*4+rr, k in [kq*32, kq*32+32)
  float4 w4r[4][8];
  #pragma unroll
  for (int rr = 0; rr < 4; rr++) {
    const int rho = rg * 4 + rr;
    const int g = (rho >> 5) * 256 + s * 32 + (rho & 31);
    const float4* src = (const float4*)(whD + (size_t)g * 256 + kq * 32);
    #pragma unroll
    for (int q = 0; q < 8; q++) w4r[rr][q] = src[q];
  }
  for (int f = t; f < 4 * 288; f += 256) h_sh[f] = 0.f;   // h0 = 0
  float c0 = 0.f;                                          // cell state (t<128)
  __syncthreads();

  for (int step = 0; step < 512; step++) {
    const int n = dir ? (511 - step) : step;
    // prefetch gi for this step (hidden under the matvec)
    float gpre[4];
    if (t < 128) {
      #pragma unroll
      for (int gg = 0; gg < 4; gg++)
        gpre[gg] = giD[(size_t)(b2 * 512 + n) * 1024 + gg * 256 + s * 32 + jj];
    }
    // matvec partials over this thread's k-slice
    float acc[4][4] = {};
    #pragma unroll
    for (int q = 0; q < 8; q++) {
      float4 h0 = *(const float4*)&h_sh[0*288 + kq*36 + q*4];
      float4 h1 = *(const float4*)&h_sh[1*288 + kq*36 + q*4];
      float4 h2 = *(const float4*)&h_sh[2*288 + kq*36 + q*4];
      float4 h3 = *(const float4*)&h_sh[3*288 + kq*36 + q*4];
      #pragma unroll
      for (int rr = 0; rr < 4; rr++) {
        float4 w = w4r[rr][q];
        acc[rr][0] += w.x*h0.x + w.y*h0.y + w.z*h0.z + w.w*h0.w;
        acc[rr][1] += w.x*h1.x + w.y*h1.y + w.z*h1.z + w.w*h1.w;
        acc[rr][2] += w.x*h2.x + w.y*h2.y + w.z*h2.z + w.w*h2.w;
        acc[rr][3] += w.x*h3.x + w.y*h3.y + w.z*h3.z + w.w*h3.w;
      }
    }
    // reduce across kq (lane bits 0..2) in-register
    #pragma unroll
    for (int m = 1; m <= 4; m <<= 1) {
      #pragma unroll
      for (int rr = 0; rr < 4; rr++) {
        #pragma unroll
        for (int b = 0; b < 4; b++)
          acc[rr][b] += __shfl_xor(acc[rr][b], m, 64);
      }
    }
    if (kq == 0) {
      #pragma unroll
      for (int rr = 0; rr < 4; rr++) {
        const int rho = rg * 4 + rr;
        *(float4*)&gsh[rho * 4] = make_float4(acc[rr][0], acc[rr][1], acc[rr][2], acc[rr][3]);
      }
    }
    __syncthreads();   // gsh ready; h_sh reads complete (safe to overwrite below)

    const unsigned long long tag = (unsigned long long)(step + 1);
    const int buf = (step + 1) & 1;
    if (t < 128) {
      const float g_i = gsh[(0*32 + jj)*4 + b2] + gpre[0];
      const float g_f = gsh[(1*32 + jj)*4 + b2] + gpre[1];
      const float g_g = gsh[(2*32 + jj)*4 + b2] + gpre[2];
      const float g_o = gsh[(3*32 + jj)*4 + b2] + gpre[3];
      c0 = sigmoidf_(g_f) * c0 + sigmoidf_(g_i) * tanhf(g_g);
      const float hv = sigmoidf_(g_o) * tanhf(c0);
      const unsigned long long pk = (tag << 32) | (unsigned long long)__float_as_uint(hv);
      __hip_atomic_store(hdD + buf * 1024 + b2 * 256 + s * 32 + jj, pk,
                         __ATOMIC_RELAXED, __HIP_MEMORY_SCOPE_AGENT);
      hs[(size_t)(b2 * 512 + n) * 512 + dir * 256 + s * 32 + jj] = hv;
      h_sh[b2 * 288 + s * 36 + jj] = hv;     // own slice direct to LDS
    }
    // consume remote slices (tag-polled, relaxed)
    if (step != 511 && ck != s) {
      const unsigned long long* src = hdD + buf * 1024 + cb * 256 + ck * 32 + ci;
      unsigned long long v0, v1, v2, v3;
      for (;;) {
        v0 = __hip_atomic_load(src + 0, __ATOMIC_RELAXED, __HIP_MEMORY_SCOPE_AGENT);
        v1 = __hip_atomic_load(src + 1, __ATOMIC_RELAXED, __HIP_MEMORY_SCOPE_AGENT);
        v2 = __hip_atomic_load(src + 2, __ATOMIC_RELAXED, __HIP_MEMORY_SCOPE_AGENT);
        v3 = __hip_atomic_load(src + 3, __ATOMIC_RELAXED, __HIP_MEMORY_SCOPE_AGENT);
        if ((v0 >> 32) >= tag && (v1 >> 32) >= tag && (v2 >> 32) >= tag && (v3 >> 32) >= tag) break;
        __builtin_amdgcn_s_sleep(1);
      }
      float* dst = &h_sh[cb * 288 + ck * 36 + ci];
      dst[0] = __uint_as_float((unsigned)v0);
      dst[1] = __uint_as_float((unsigned)v1);
      dst[2] = __uint_as_float((unsigned)v2);
      dst[3] = __uint_as_float((unsigned)v3);
    }
    __syncthreads();   // h_sh complete for next step
  }
}

// ---------------- final head ----------------
__global__ __launch_bounds__(256) void fc_k(const float* __restrict__ hs, const float* __restrict__ fw,
                                            const float* __restrict__ fb, float* __restrict__ out)
{
  const int t = threadIdx.x;
  float p[4] = {};
  for (int j = t; j < 512; j += 256) {
    const float w = fw[j];
    #pragma unroll
    for (int b = 0; b < 4; b++) p[b] += hs[(size_t)(b * 512 + 511) * 512 + j] * w;
  }
  #pragma unroll
  for (int b = 0; b < 4; b++)
    #pragma unroll
    for (int o = 32; o >= 1; o >>= 1) p[b] += __shfl_xor(p[b], o, 64);
  __shared__ float r4[4][4];
  const int wid = t >> 6, lane = t & 63;
  if (lane == 0) {
    #pragma unroll
    for (int b = 0; b < 4; b++) r4[b][wid] = p[b];
  }
  __syncthreads();
  if (t == 0) {
    #pragma unroll
    for (int b = 0; b < 4; b++) out[b] = r4[b][0] + r4[b][1] + r4[b][2] + r4[b][3] + fb[0];
  }
}

// ---------------- host ----------------
extern "C" void kernel_launch(void* const* d_in, const int* in_sizes, int n_in,
                              void* d_out, int out_size, void* d_ws, size_t ws_size,
                              hipStream_t stream) {
  (void)in_sizes; (void)n_in; (void)out_size; (void)ws_size;
  const float* x     = (const float*)d_in[0];
  const float* Win_w = (const float*)d_in[1];
  const float* Win_b = (const float*)d_in[2];
  const float* ln1w  = (const float*)d_in[3];
  const float* ln1b  = (const float*)d_in[4];
  const float* Wq    = (const float*)d_in[5];
  const float* bq    = (const float*)d_in[6];
  const float* Wk    = (const float*)d_in[7];
  const float* bk    = (const float*)d_in[8];
  const float* Wv    = (const float*)d_in[9];
  const float* bv    = (const float*)d_in[10];
  const float* Wo    = (const float*)d_in[11];
  const float* bo    = (const float*)d_in[12];
  const float* proj  = (const float*)d_in[13];
  const float* ln2w  = (const float*)d_in[14];
  const float* ln2b  = (const float*)d_in[15];
  const float* Wff1  = (const float*)d_in[16];
  const float* bff1  = (const float*)d_in[17];
  const float* Wff2  = (const float*)d_in[18];
  const float* bff2  = (const float*)d_in[19];
  const float* Wih0  = (const float*)d_in[20];
  const float* Whh0  = (const float*)d_in[21];
  const float* b0    = (const float*)d_in[22];
  const float* Wih12 = (const float*)d_in[23];
  const float* Whh12 = (const float*)d_in[24];
  const float* b12   = (const float*)d_in[25];
  const float* fcw   = (const float*)d_in[26];
  const float* fcb   = (const float*)d_in[27];

  float* ws = (float*)d_ws;
  float* H   = ws + OFF_H;
  float* Y   = ws + OFF_Y;
  float* Q   = ws + OFF_Q;
  float* Kb  = ws + OFF_K;
  float* V   = ws + OFF_V;
  float* O   = ws + OFF_O;
  float* FFb = ws + OFF_FF;
  float* QP  = ws + OFF_QP;
  float* KP  = ws + OFF_KP;
  float* S   = ws + OFF_S;
  float* P   = ws + OFF_P;
  float* KS  = ws + OFF_KSUM;
  float* PK  = ws + OFF_PK;
  float* DG  = ws + OFF_DIAG;
  unsigned* KMAX = (unsigned*)(ws + OFF_KMAX);
  unsigned long long* HD = (unsigned long long*)(ws + OFF_HDBUF);
  float* GI  = ws + OFF_QP;            // reused in LSTM phase
  float* BLa = ws + OFF_FF;            // reused in LSTM phase
  float* BLb = ws + OFF_FF + 1048576;

  const dim3 blk(256);

  // input projection: N=256, K=128
  gemmA_k<<<dim3(4,32), blk, 0, stream>>>(x, Win_w, Win_b, nullptr, nullptr, H, 256, 128, 0);

  for (int l = 0; l < 8; l++) {
    const float* prj = proj + (size_t)l * 3520;
    ln_k<<<512, blk, 0, stream>>>(H, ln1w + l*256, ln1b + l*256, Y);
    // fused QKV: 3 segments of N=256
    gemmB_k<<<dim3(12,16), blk, 0, stream>>>(Y,
        Wq + (size_t)l*65536, Wk + (size_t)l*65536, Wv + (size_t)l*65536,
        bq + l*256, bk + l*256, bv + l*256,
        nullptr, nullptr, nullptr,
        Q, Kb, V, 256, 256, 4, 0);
    (void)hipMemsetAsync(KMAX, 0, 32 * sizeof(unsigned), stream);
    featqk_k<<<8192, blk, 0, stream>>>(Q, Kb, prj, QP, KP, DG, KMAX);
    featk2_k<<<7168, blk, 0, stream>>>(KP, DG, KMAX);
    csum_k<<<512, blk, 0, stream>>>(KP, V, S, KS);
    cpref_k<<<32, blk, 0, stream>>>(S, KS, P, PK);
    attn_k<<<512, blk, 0, stream>>>(QP, KP, V, P, PK, O);
    gemmA_k<<<dim3(4,32), blk, 0, stream>>>(O, Wo + (size_t)l*65536, bo + l*256, nullptr, H, H, 256, 256, 0);
    ln_k<<<512, blk, 0, stream>>>(H, ln2w + l*256, ln2b + l*256, Y);
    gemmB_k<<<dim3(16,16), blk, 0, stream>>>(Y,
        Wff1 + (size_t)l*262144, nullptr, nullptr,
        bff1 + l*1024, nullptr, nullptr,
        nullptr, nullptr, nullptr,
        FFb, nullptr, nullptr, 1024, 256, 16, 1);
    gemmA_k<<<dim3(4,32), blk, 0, stream>>>(FFb, Wff2 + (size_t)l*262144, bff2 + l*256, nullptr, H, H, 256, 1024, 0);
  }

  // ---- BiLSTM layer 0 (input H, K=256): fused both directions ----
  gemmB_k<<<dim3(32,16), blk, 0, stream>>>(H,
      Wih0, Wih0 + 262144, nullptr,
      b0, b0 + 2048, nullptr,
      b0 + 1024, b0 + 3072, nullptr,
      GI, GI + 2097152, nullptr, 1024, 256, 16, 0);
  (void)hipMemsetAsync(HD, 0, 4096 * sizeof(unsigned long long), stream);
  rec_k<<<16, blk, 0, stream>>>(GI, Whh0, BLa, HD);

  // ---- layer 1 (input BLa, K=512) ----
  gemmB_k<<<dim3(32,16), blk, 0, stream>>>(BLa,
      Wih12, Wih12 + 524288, nullptr,
      b12, b12 + 2048, nullptr,
      b12 + 1024, b12 + 3072, nullptr,
      GI, GI + 2097152, nullptr, 1024, 512, 16, 0);
  (void)hipMemsetAsync(HD, 0, 4096 * sizeof(unsigned long long), stream);
  rec_k<<<16, blk, 0, stream>>>(GI, Whh12, BLb, HD);

  // ---- layer 2 (input BLb, K=512) ----
  gemmB_k<<<dim3(32,16), blk, 0, stream>>>(BLb,
      Wih12 + 1048576, Wih12 + 1572864, nullptr,
      b12 + 4096, b12 + 6144, nullptr,
      b12 + 5120, b12 + 7168, nullptr,
      GI, GI + 2097152, nullptr, 1024, 512, 16, 0);
  (void)hipMemsetAsync(HD, 0, 4096 * sizeof(unsigned long long), stream);
  rec_k<<<16, blk, 0, stream>>>(GI, Whh12 + 524288, BLa, HD);

  fc_k<<<1, blk, 0, stream>>>(BLa, fcw, fcb, (float*)d_out);
}